// Round 14
// baseline (179.567 us; speedup 1.0000x reference)
//
#include <hip/hip_runtime.h>

typedef __attribute__((ext_vector_type(8))) short bf16x8;
typedef __attribute__((ext_vector_type(4))) float f32x4;

#define BTOT 32768
#define FDIM 128
#define TDIM 32
#define DDIM 16
#define HDIM 10
#define CDIM 320
#define ALPHA_C 0.1f
#define MARGIN_C 1.0f
#define SLOPE_C 0.2f
#define OFFSET_C 1.0e6f

// ws float offsets
#define WS_A0P  0           // 32 t x 16 o x 128 n bf16 = 65536 shorts
#define WS_MEAN 32768
#define WS_TC   33088
#define WS_CE   33152

#define YSROW 163           // floats; 163%32=3 -> writes <=2-way, reads conflict-free

__device__ __forceinline__ float leaky(float x) { return fmaxf(x, SLOPE_C * x); }

__device__ __forceinline__ unsigned short f2bf(float f) {   // RNE f32->bf16
    unsigned int u = __float_as_uint(f);
    u += 0x7fffu + ((u >> 16) & 1u);
    return (unsigned short)(u >> 16);
}

__device__ __forceinline__ f32x4 mfma32(bf16x8 a, bf16x8 b, f32x4 c) {
    return __builtin_amdgcn_mfma_f32_16x16x32_bf16(a, b, c, 0, 0, 0);
}

// a0p[t][o(16, zero-pad>=10)][n(128)] bf16 : per-t A-operand table, A[m=o][k=n]
__global__ void prep_kernel(const float* __restrict__ aw, const float* __restrict__ W0,
                            unsigned short* __restrict__ a0p) {
    int idx = blockIdx.x * blockDim.x + threadIdx.x;   // 65536
    if (idx >= 65536) return;
    int n = idx & 127, o = (idx >> 7) & 15, t = idx >> 11;
    unsigned short r = 0;
    if (o < 10) {
        const float* a = aw + ((size_t)t * FDIM + n) * DDIM;
        const float* w = W0 + o * DDIM;
        float s = 0.f;
#pragma unroll
        for (int d = 0; d < DDIM; ++d) s += a[d] * w[d];
        r = f2bf(s);
    }
    a0p[idx] = r;
}

// L0 on MFMA (32 independent MFMAs/wave) -> ys LDS -> VALU W1..W3 chain -> rep.
// No head/CE here. Grid 2048 = 1024 bchunk x 2 thalf; block 256 = 4 waves.
__global__ __launch_bounds__(256, 4) void gemm0_fused(
    const float* __restrict__ X, const unsigned short* __restrict__ a0p,
    const float* __restrict__ W1, const float* __restrict__ W2,
    const float* __restrict__ W3,
    float* __restrict__ rep)
{
    __shared__ __align__(16) char ldsbuf[32 * YSROW * 4];   // 20864 B
    unsigned short (*xs)[136] = (unsigned short (*)[136])ldsbuf;  // overlay (dead after frags)
    float* ysf = (float*)ldsbuf;

    int tid = threadIdx.x;
    int b0 = (blockIdx.x >> 1) * 32;
    int thalf = blockIdx.x & 1;

    // ---- stage X (32x128 f32 -> bf16), coalesced ----
#pragma unroll
    for (int k = 0; k < 4; ++k) {
        int idx = tid + k * 256;             // 1024 float4
        int row = idx >> 5, col4 = idx & 31;
        float4 v = reinterpret_cast<const float4*>(X + (size_t)(b0 + row) * FDIM)[col4];
        unsigned p0, p1;
        asm("v_cvt_pk_bf16_f32 %0, %1, %2" : "=v"(p0) : "v"(v.x), "v"(v.y));
        asm("v_cvt_pk_bf16_f32 %0, %1, %2" : "=v"(p1) : "v"(v.z), "v"(v.w));
        uint2 pk; pk.x = p0; pk.y = p1;
        *reinterpret_cast<uint2*>(&xs[row][col4 * 4]) = pk;
    }
    __syncthreads();

    int lane = tid & 63, w = __builtin_amdgcn_readfirstlane(tid >> 6);
    int r16 = lane & 15, g = lane >> 4;
    int bsub = w >> 1, tq = w & 1;

    // B-operand X frags (j=b on r16), identical k-map as A (permutation-safe)
    bf16x8 xf[4];
#pragma unroll
    for (int s = 0; s < 4; ++s)
        xf[s] = *reinterpret_cast<const bf16x8*>(&xs[bsub * 16 + r16][s * 32 + g * 8]);
    __syncthreads();                         // xs dead -> ys live

    // ---- L0: 8 t's x 4 MFMA, all independent; raw acc -> ys ----
    int rowb = (bsub * 16 + r16) * YSROW;
#pragma unroll
    for (int tt = 0; tt < 8; ++tt) {
        int t = thalf * 16 + tq * 8 + tt;
        const bf16x8* ap = reinterpret_cast<const bf16x8*>(
            a0p + ((size_t)t * 16 + r16) * 128);
        f32x4 a0 = {0.f, 0.f, 0.f, 0.f}, a1 = {0.f, 0.f, 0.f, 0.f};
        a0 = mfma32(ap[0 * 4 + g], xf[0], a0);
        a1 = mfma32(ap[1 * 4 + g], xf[1], a1);
        a0 = mfma32(ap[2 * 4 + g], xf[2], a0);
        a1 = mfma32(ap[3 * 4 + g], xf[3], a1);
        int colb = (tq * 8 + tt) * 10 + g * 4;   // o = g*4+r, only o<10 stored
        if (g < 2) {
            ysf[rowb + colb + 0] = a0[0] + a1[0];
            ysf[rowb + colb + 1] = a0[1] + a1[1];
            ysf[rowb + colb + 2] = a0[2] + a1[2];
            ysf[rowb + colb + 3] = a0[3] + a1[3];
        } else if (g == 2) {
            ysf[rowb + colb + 0] = a0[0] + a1[0];
            ysf[rowb + colb + 1] = a0[1] + a1[1];
        }
    }
    __syncthreads();                         // ys complete

    // ---- VALU chain epilogue: 2 (b,t) pairs per thread, ILP-10, no cross-lane ----
    int bl = tid >> 3, t8 = tid & 7;
#pragma unroll
    for (int p = 0; p < 2; ++p) {
        int tloc = t8 + p * 8;               // 0..15
        const float* yrow = ysf + bl * YSROW + tloc * 10;
        float h[HDIM], lh[HDIM], gg[HDIM];
#pragma unroll
        for (int o = 0; o < HDIM; ++o) h[o] = yrow[o];
#pragma unroll
        for (int o = 0; o < HDIM; ++o) lh[o] = leaky(h[o]);
#pragma unroll
        for (int o = 0; o < HDIM; ++o) { float s = 0.f;
#pragma unroll
            for (int i = 0; i < HDIM; ++i) s += W1[o * HDIM + i] * lh[i]; gg[o] = s; }
#pragma unroll
        for (int o = 0; o < HDIM; ++o) lh[o] = leaky(gg[o]);
#pragma unroll
        for (int o = 0; o < HDIM; ++o) { float s = 0.f;
#pragma unroll
            for (int i = 0; i < HDIM; ++i) s += W2[o * HDIM + i] * lh[i]; h[o] = s; }
#pragma unroll
        for (int o = 0; o < HDIM; ++o) lh[o] = leaky(h[o]);
#pragma unroll
        for (int o = 0; o < HDIM; ++o) { float s = 0.f;
#pragma unroll
            for (int i = 0; i < HDIM; ++i) s += W3[o * HDIM + i] * lh[i]; gg[o] = s; }

        float* rp = rep + (size_t)(b0 + bl) * CDIM + (thalf * 16 + tloc) * HDIM;
#pragma unroll
        for (int q = 0; q < 5; ++q) {
            float2 v; v.x = gg[2 * q]; v.y = gg[2 * q + 1];
            reinterpret_cast<float2*>(rp)[q] = v;
        }
    }
}

// mean accumulation: block = 320 threads (one per (t,h)), 128 b's per block, coalesced
__global__ void meanred_kernel(const float* __restrict__ rep, float* __restrict__ mean_acc)
{
    int j = threadIdx.x;                   // 0..319
    const float* base = rep + (size_t)blockIdx.x * 128 * CDIM;
    float s0 = 0, s1 = 0, s2 = 0, s3 = 0;
    for (int b = 0; b < 128; b += 4) {
        s0 += base[(size_t)(b + 0) * CDIM + j];
        s1 += base[(size_t)(b + 1) * CDIM + j];
        s2 += base[(size_t)(b + 2) * CDIM + j];
        s3 += base[(size_t)(b + 3) * CDIM + j];
    }
    atomicAdd(&mean_acc[j], s0 + s1 + s2 + s3);
}

// Triplet-center hinge + head/CE fused. Block = 32 b's staged in LDS,
// thread = (t, 4 b's); rv[] feeds BOTH the hinge and the head (no extra loads).
__global__ __launch_bounds__(256) void tc_head_kernel(const float* __restrict__ rep,
    const float* __restrict__ mean_acc,
    const float* __restrict__ Wh, const float* __restrict__ bh,
    float* __restrict__ tc_sum, float* __restrict__ ce_out)
{
    __shared__ float tile[32][CDIM];     // 40 KB
    __shared__ float mm[CDIM];
    __shared__ float msq[TDIM];
    __shared__ float cep[32][33];        // +1 pad: tree-read conflict-free
    __shared__ float wpart[4];
    int tid = threadIdx.x;
    int b0 = blockIdx.x * 32;

    for (int i = tid; i < CDIM; i += 256) mm[i] = mean_acc[i] * (1.f / BTOT);
    const float4* src = reinterpret_cast<const float4*>(rep + (size_t)b0 * CDIM);
#pragma unroll
    for (int k = 0; k < 10; ++k) {       // 2560 float4, coalesced
        int idx = tid + k * 256;
        int row = idx / 80, col4 = idx - row * 80;
        *reinterpret_cast<float4*>(&tile[row][col4 * 4]) = src[idx];
    }
    __syncthreads();
    if (tid < TDIM) {
        float s = 0.f;
#pragma unroll
        for (int h = 0; h < HDIM; ++h) { float v = mm[tid * HDIM + h]; s += v * v; }
        msq[tid] = s;
    }
    __syncthreads();

    int t = tid & 31, bg = tid >> 5;     // 8 b-groups x 4 b's
    float rv[4][HDIM], rsq[4];
#pragma unroll
    for (int j = 0; j < 4; ++j) {
        const float* rp = &tile[bg * 4 + j][t * HDIM];
        float s = 0.f;
#pragma unroll
        for (int q = 0; q < 5; ++q) {
            float2 v = reinterpret_cast<const float2*>(rp)[q];
            rv[j][2 * q] = v.x; rv[j][2 * q + 1] = v.y;
            s += v.x * v.x + v.y * v.y;
        }
        rsq[j] = s;
    }

    // ---- hinge ----
    float pos[4], neg[4];
#pragma unroll
    for (int j = 0; j < 4; ++j) { pos[j] = 0.f; neg[j] = 1e30f; }
#pragma unroll 4
    for (int c = 0; c < TDIM; ++c) {
        float m0[HDIM];
#pragma unroll
        for (int q = 0; q < 5; ++q) {
            float2 v = reinterpret_cast<const float2*>(&mm[c * HDIM])[q];
            m0[2 * q] = v.x; m0[2 * q + 1] = v.y;
        }
        float mq = msq[c];
        bool isT = (c == t);
#pragma unroll
        for (int j = 0; j < 4; ++j) {
            float dot = 0.f;
#pragma unroll
            for (int h = 0; h < HDIM; ++h) dot += rv[j][h] * m0[h];
            float s = rsq[j] - 2.f * dot + mq;
            if (isT) pos[j] = s;
            float s2 = isT ? s + OFFSET_C : s;
            neg[j] = fminf(neg[j], s2);
        }
    }
    float hs = 0.f;
#pragma unroll
    for (int j = 0; j < 4; ++j) hs += fmaxf(pos[j] + MARGIN_C - neg[j], 0.f);
#pragma unroll
    for (int m = 1; m < 64; m <<= 1) hs += __shfl_xor(hs, m, 64);
    int lane = tid & 63, w = tid >> 6;
    if (lane == 0) wpart[w] = hs;

    // ---- head + CE (online single-exp LSE, branchless; R8-proven math) ----
#pragma unroll
    for (int j = 0; j < 4; ++j) {
        float lh[HDIM];
#pragma unroll
        for (int o = 0; o < HDIM; ++o) lh[o] = leaky(rv[j][o]);
        float m = -1e30f, se = 0.f, pt = 0.f;
#pragma unroll
        for (int o = 0; o < TDIM; ++o) {
            float s = bh[o];
#pragma unroll
            for (int i = 0; i < HDIM; ++i) s += Wh[o * HDIM + i] * lh[i];
            pt = (o == t) ? s : pt;
            float d = s - m;
            float e = __expf(-fabsf(d));
            se = (d > 0.f) ? se * e + 1.f : se + e;
            m = fmaxf(m, s);
        }
        cep[bg * 4 + j][t] = m + __logf(se) - pt;
    }
    __syncthreads();
    if (tid < 32) {
        float s = 0.f;
#pragma unroll
        for (int k = 0; k < 32; ++k) s += cep[tid][k];
        ce_out[b0 + tid] = s * (1.f / TDIM);
    }
    if (tid == 0) atomicAdd(tc_sum, wpart[0] + wpart[1] + wpart[2] + wpart[3]);
}

__global__ void final_kernel(const float* __restrict__ ce_out,
                             const float* __restrict__ tc_sum, float* __restrict__ loss)
{
    int b = blockIdx.x * blockDim.x + threadIdx.x;
    if (b < BTOT)
        loss[b] = ALPHA_C * (tc_sum[0] * (1.f / ((float)BTOT * TDIM))) + ce_out[b];
}

extern "C" void kernel_launch(void* const* d_in, const int* in_sizes, int n_in,
                              void* d_out, int out_size, void* d_ws, size_t ws_size,
                              hipStream_t stream) {
    const float* X  = (const float*)d_in[0];
    const float* aw = (const float*)d_in[1];
    const float* W0 = (const float*)d_in[2];
    const float* W1 = (const float*)d_in[3];
    const float* W2 = (const float*)d_in[4];
    const float* W3 = (const float*)d_in[5];
    const float* Wh = (const float*)d_in[6];
    const float* bh = (const float*)d_in[7];
    float* ws = (float*)d_ws;
    unsigned short* a0p = (unsigned short*)(ws + WS_A0P);
    float* mean_acc = ws + WS_MEAN;
    float* tc_sum   = ws + WS_TC;
    float* ce_out   = ws + WS_CE;
    float* out_rep = (float*)d_out;        // [32768][320]
    float* loss = out_rep + (size_t)BTOT * TDIM * HDIM;

    // zero mean_acc + tc (384 floats); ce_out is direct-written
    hipMemsetAsync(mean_acc, 0, 384 * sizeof(float), stream);
    prep_kernel<<<256, 256, 0, stream>>>(aw, W0, a0p);
    gemm0_fused<<<2048, 256, 0, stream>>>(X, a0p, W1, W2, W3, out_rep);
    meanred_kernel<<<256, 320, 0, stream>>>(out_rep, mean_acc);
    tc_head_kernel<<<BTOT / 32, 256, 0, stream>>>(out_rep, mean_acc, Wh, bh,
                                                  tc_sum, ce_out);
    final_kernel<<<BTOT / 256, 256, 0, stream>>>(ce_out, tc_sum, loss);
}